// Round 3
// baseline (64065.485 us; speedup 1.0000x reference)
//
#include <hip/hip_runtime.h>

// Problem constants
#define Bn 128
#define Tn 512
#define Vn 128
#define En 64
#define Ln 128
#define Hn 512
#define G4 2048
#define WGS 128
#define NTHR 512
#define NALL 65536

typedef unsigned short u16;
typedef unsigned int u32;
typedef __bf16 bf16x8 __attribute__((ext_vector_type(8)));
typedef float f32x4 __attribute__((ext_vector_type(4)));

__device__ inline float bf2f(u16 h) {
    u32 u = ((u32)h) << 16;
    float f;
    __builtin_memcpy(&f, &u, 4);
    return f;
}
__device__ inline u16 f2bf(float f) {
    u32 u;
    __builtin_memcpy(&u, &f, 4);
    u32 r = (u + 0x7fffu + ((u >> 16) & 1u)) >> 16;
    return (u16)r;
}
__device__ inline float sigm(float x) { return 1.f / (1.f + expf(-x)); }
__device__ inline float leaky(float x) { return x > 0.f ? x : 0.2f * x; }
__device__ inline float softplus(float x) {
    return x > 0.f ? x + log1pf(expf(-x)) : log1pf(expf(x));
}

// Workspace layout (bytes); total ~17.8 MB
#define OFF_FLAGS  0x000000
#define OFF_PREV   0x001000
#define OFF_B1SUM  0x002000
#define OFF_WP     0x004000
#define OFF_BIAS0  0x008000
#define OFF_CPAR   0x00A000   // 4096 f32: cg1,cbeta1,cg2,cbeta2; bo1@2048, bo2@2304, cb2@2560, cb1@3072, wo2f@3584
#define OFF_H0HI   0x010000   // 128KB bf16 (128x512)
#define OFF_H0LO   0x030000
#define OFF_H1HI   0x050000
#define OFF_H1LO   0x070000
#define OFF_HEAD1F 0x090000   // 128KB f32 (128x256)
#define OFF_WO1TH  0x0B0000   // 256KB bf16 (256x512)
#define OFF_WO1TL  0x0F0000
#define OFF_ZF     0x130000   // 64KB f32
#define OFF_CW1F   0x140000   // 256KB f32
#define OFF_CW2F   0x180000   // 1MB f32
#define OFF_CONDF  0x280000   // 256KB f32
#define OFF_YBUF   0x2C0000   // 256KB f32
#define OFF_BASE0  0x300000   // 1MB f32 (temp: wo1f in P0/P1)
#define OFF_EMBW   0x400000   // 1MB f32
#define OFF_W0HI   0x500000   // 2MB bf16 (2048x512) each
#define OFF_W0LO   0x700000
#define OFF_W1HI   0x900000
#define OFF_W1LO   0xB00000
#define OFF_WI1HI  0xD00000
#define OFF_WI1LO  0xF00000   // end 0x1100000

// -------- grid barrier (128 WGs, all resident) --------
__device__ inline void gbar(int* cnt, int* gen) {
    __syncthreads();
    if (threadIdx.x == 0) {
        __threadfence();
        int g = __hip_atomic_load(gen, __ATOMIC_RELAXED, __HIP_MEMORY_SCOPE_AGENT);
        int arrived = __hip_atomic_fetch_add(cnt, 1, __ATOMIC_ACQ_REL, __HIP_MEMORY_SCOPE_AGENT);
        if (arrived == WGS - 1) {
            __hip_atomic_store(cnt, 0, __ATOMIC_RELAXED, __HIP_MEMORY_SCOPE_AGENT);
            __hip_atomic_store(gen, g + 1, __ATOMIC_RELEASE, __HIP_MEMORY_SCOPE_AGENT);
        } else {
            while (__hip_atomic_load(gen, __ATOMIC_ACQUIRE, __HIP_MEMORY_SCOPE_AGENT) == g)
                __builtin_amdgcn_s_sleep(1);
        }
        __threadfence();
    }
    __syncthreads();
}

// Split-bf16 16x16 tile: D = Ahi·Bhi^T + Alo·Bhi^T + Ahi·Blo^T (3 indep chains)
__device__ inline f32x4 mfma_tile3(const u16* __restrict__ Ahi, const u16* __restrict__ Alo,
                                   int lda, const u16* __restrict__ Bhi,
                                   const u16* __restrict__ Blo, int ldb,
                                   int row0, int col0, int K) {
    const int lane = threadIdx.x & 63;
    const int n = lane & 15;
    const int q = lane >> 4;
    const size_t ao = (size_t)(row0 + n) * lda + q * 8;
    const size_t bo = (size_t)(col0 + n) * ldb + q * 8;
    f32x4 a1 = {0.f, 0.f, 0.f, 0.f}, a2 = a1, a3 = a1;
#pragma unroll 4
    for (int k = 0; k < K; k += 32) {
        bf16x8 ah = *reinterpret_cast<const bf16x8*>(Ahi + ao + k);
        bf16x8 al = *reinterpret_cast<const bf16x8*>(Alo + ao + k);
        bf16x8 bh = *reinterpret_cast<const bf16x8*>(Bhi + bo + k);
        bf16x8 bl = *reinterpret_cast<const bf16x8*>(Blo + bo + k);
        a1 = __builtin_amdgcn_mfma_f32_16x16x32_bf16(ah, bh, a1, 0, 0, 0);
        a2 = __builtin_amdgcn_mfma_f32_16x16x32_bf16(al, bh, a2, 0, 0, 0);
        a3 = __builtin_amdgcn_mfma_f32_16x16x32_bf16(ah, bl, a3, 0, 0, 0);
    }
    return a1 + a2 + a3;
}

// dtype-safe staging
__device__ inline void stage(float* dst, const void* src, int n, int gtid, bool isbf) {
    if (isbf) {
        const u16* s = (const u16*)src;
        for (int e = gtid; e < n; e += NALL) dst[e] = bf2f(s[e]);
    } else {
        const float* s = (const float*)src;
        for (int e = gtid; e < n; e += NALL) dst[e] = s[e];
    }
}
// split staging: hi = bf16(w), lo = bf16(w - hi)
__device__ inline void stage_split(u16* hi, u16* lo, const void* src, int n, int gtid, bool isbf) {
    if (isbf) {
        const u16* s = (const u16*)src;
        for (int e = gtid; e < n; e += NALL) { hi[e] = s[e]; lo[e] = 0; }
    } else {
        const float* s = (const float*)src;
        for (int e = gtid; e < n; e += NALL) {
            float w = s[e];
            u16 h = f2bf(w);
            hi[e] = h;
            lo[e] = f2bf(w - bf2f(h));
        }
    }
}

template <bool ISBF>
__device__ inline float ldw(const void* p, size_t i) {
    if constexpr (ISBF) return bf2f(((const u16*)p)[i]);
    else return ((const float*)p)[i];
}

// base0 = cond @ wih0[:,64:576]^T + bih0 + bhh0 ; embW = emb @ wih0[:,0:64]^T (fp32)
template <bool ISBF>
__device__ void phase5(const void* wih0, const void* emb, const float* __restrict__ condf,
                       const float* __restrict__ bias0f, float* __restrict__ base0,
                       float* __restrict__ embW, int gtid) {
    const int cc = gtid & 2047;
    const int bb0 = gtid >> 11;  // 0..31
    float b = bias0f[cc];
    float a0 = b, a1 = b, a2 = b, a3 = b;
    const float* c0p = condf + (size_t)bb0 * Hn;
    const float* c1p = condf + (size_t)(bb0 + 32) * Hn;
    const float* c2p = condf + (size_t)(bb0 + 64) * Hn;
    const float* c3p = condf + (size_t)(bb0 + 96) * Hn;
    const size_t wb = (size_t)cc * 578 + 64;
    for (int k = 0; k < Hn; ++k) {
        float w = ldw<ISBF>(wih0, wb + k);
        a0 += c0p[k] * w; a1 += c1p[k] * w; a2 += c2p[k] * w; a3 += c3p[k] * w;
    }
    base0[(size_t)bb0 * G4 + cc] = a0;
    base0[(size_t)(bb0 + 32) * G4 + cc] = a1;
    base0[(size_t)(bb0 + 64) * G4 + cc] = a2;
    base0[(size_t)(bb0 + 96) * G4 + cc] = a3;
    float e0 = 0.f, e1 = 0.f, e2 = 0.f, e3 = 0.f;
    const size_t wb2 = (size_t)cc * 578;
    for (int k = 0; k < En; ++k) {
        float w = ldw<ISBF>(wih0, wb2 + k);
        e0 += ldw<ISBF>(emb, (size_t)bb0 * En + k) * w;
        e1 += ldw<ISBF>(emb, (size_t)(bb0 + 32) * En + k) * w;
        e2 += ldw<ISBF>(emb, (size_t)(bb0 + 64) * En + k) * w;
        e3 += ldw<ISBF>(emb, (size_t)(bb0 + 96) * En + k) * w;
    }
    embW[(size_t)bb0 * G4 + cc] = e0;
    embW[(size_t)(bb0 + 32) * G4 + cc] = e1;
    embW[(size_t)(bb0 + 64) * G4 + cc] = e2;
    embW[(size_t)(bb0 + 96) * G4 + cc] = e3;
}

// LayerNorm + LeakyReLU over one row of 512 (one WG)
__device__ inline void ln_leaky_row(const float* __restrict__ x, const float* __restrict__ gamma,
                                    const float* __restrict__ beta, float* __restrict__ out,
                                    float* red) {
    int tid = threadIdx.x;
    float v = x[tid];
    float s = v, s2 = v * v;
    for (int off = 32; off; off >>= 1) {
        s += __shfl_down(s, off);
        s2 += __shfl_down(s2, off);
    }
    int wv = tid >> 6;
    if ((tid & 63) == 0) { red[wv * 2] = s; red[wv * 2 + 1] = s2; }
    __syncthreads();
    if (tid == 0) {
        float ts = 0.f, ts2 = 0.f;
        for (int i = 0; i < 8; ++i) { ts += red[i * 2]; ts2 += red[i * 2 + 1]; }
        float m = ts / 512.f;
        float var = ts2 / 512.f - m * m;
        red[16] = m;
        red[17] = rsqrtf(var + 1e-5f);
    }
    __syncthreads();
    float m = red[16], rs = red[17];
    out[tid] = leaky((v - m) * rs * gamma[tid] + beta[tid]);
    __syncthreads();
}

__device__ inline void head_phase(int tt, int ep, int g,
                                  const u16* __restrict__ h1hi, const u16* __restrict__ h1lo,
                                  const u16* __restrict__ wo1Th, const u16* __restrict__ wo1Tl,
                                  const float* __restrict__ bo1f, const float* __restrict__ wo2f,
                                  const float* __restrict__ bo2f, float* __restrict__ head1f,
                                  float* __restrict__ prevb, void* outp, bool isbf,
                                  int* headcnt) {
    const int lane = threadIdx.x & 63;
    const int n = lane & 15;
    const int q = lane >> 4;
    // head1: one 16x16 tile per WG (8 row-tiles x 16 col-tiles), fp32 result
    {
        int r0 = (g >> 4) * 16, c0 = (g & 15) * 16;
        f32x4 a = mfma_tile3(h1hi, h1lo, Hn, wo1Th, wo1Tl, Hn, r0, c0, Hn);
#pragma unroll
        for (int r = 0; r < 4; ++r) {
            int rr = r0 + q * 4 + r, cc = c0 + n;
            head1f[rr * 256 + cc] = leaky(a[r] + bo1f[cc]);
        }
        __threadfence();
        if (lane == 0)
            __hip_atomic_fetch_add(headcnt, 1, __ATOMIC_RELEASE, __HIP_MEMORY_SCOPE_AGENT);
    }
    // head2: WGs 0..7, exact fp32 dot; 16 batches x 2 outputs per WG
    if (g < 8) {
        int target = ep * WGS;
        while (__hip_atomic_load(headcnt, __ATOMIC_ACQUIRE, __HIP_MEMORY_SCOPE_AGENT) < target)
            __builtin_amdgcn_s_sleep(1);
        __threadfence();
        if (lane < 32) {
            int bl = lane >> 1, jo = lane & 1;
            int b = g * 16 + bl;
            float s = bo2f[jo];
            const float* hr = head1f + b * 256;
#pragma unroll 8
            for (int k = 0; k < 256; ++k) s += hr[k] * wo2f[k * 2 + jo];
            float y = softplus(s) + 0.005f;
            prevb[b * 2 + jo] = y;
            size_t oi = ((size_t)b * Tn + tt) * 2 + jo;
            if (isbf) ((u16*)outp)[oi] = f2bf(y);
            else ((float*)outp)[oi] = y;
        }
    }
}

__global__ void init_flags_kernel(int* flags) { flags[threadIdx.x] = 0; }

__global__ __launch_bounds__(NTHR, 1) void gen_kernel(
    const int* __restrict__ char_ids, const void* z, const void* emb,
    const void* cw1, const void* cb1, const void* cg1, const void* cbeta1,
    const void* cw2, const void* cb2, const void* cg2, const void* cbeta2,
    const void* wih0, const void* whh0, const void* bih0, const void* bhh0,
    const void* wih1, const void* whh1, const void* bih1, const void* bhh1,
    const void* wo1, const void* bo1, const void* wo2, const void* bo2,
    const void* init_t, void* outp, char* __restrict__ ws) {
    __shared__ float smem[2048 + 32];
    float* red = smem + 2048;

    int* flags = (int*)(ws + OFF_FLAGS);
    int* bcnt = flags + 0;
    int* bgen = flags + 1;
    int* headcnt = flags + 2;
    float* prevb = (float*)(ws + OFF_PREV);
    float* b1sum = (float*)(ws + OFF_B1SUM);
    float* wpb = (float*)(ws + OFF_WP);
    float* bias0f = (float*)(ws + OFF_BIAS0);
    float* cpar = (float*)(ws + OFF_CPAR);
    u16* h0hi = (u16*)(ws + OFF_H0HI);
    u16* h0lo = (u16*)(ws + OFF_H0LO);
    u16* h1hi = (u16*)(ws + OFF_H1HI);
    u16* h1lo = (u16*)(ws + OFF_H1LO);
    float* head1f = (float*)(ws + OFF_HEAD1F);
    u16* wo1Th = (u16*)(ws + OFF_WO1TH);
    u16* wo1Tl = (u16*)(ws + OFF_WO1TL);
    float* zf = (float*)(ws + OFF_ZF);
    float* cw1f = (float*)(ws + OFF_CW1F);
    float* cw2f = (float*)(ws + OFF_CW2F);
    float* condf = (float*)(ws + OFF_CONDF);
    float* ybuf = (float*)(ws + OFF_YBUF);
    float* base0 = (float*)(ws + OFF_BASE0);
    float* embW = (float*)(ws + OFF_EMBW);
    u16* W0hi = (u16*)(ws + OFF_W0HI);
    u16* W0lo = (u16*)(ws + OFF_W0LO);
    u16* W1hi = (u16*)(ws + OFF_W1HI);
    u16* W1lo = (u16*)(ws + OFF_W1LO);
    u16* Wi1hi = (u16*)(ws + OFF_WI1HI);
    u16* Wi1lo = (u16*)(ws + OFF_WI1LO);
    float* wo1f = base0;  // temp until P5

    // dtype probe: cg1 == ones -> fp32 word 0x3F800000, bf16 pair 0x3F803F80
    const bool isbf = (((const u32*)cg1)[0] == 0x3F803F80u);

    const int g = blockIdx.x;
    const int tid = threadIdx.x;
    const int wv = tid >> 6;
    const int rq = g >> 5;
    const int ut = g & 31;
    const int gw = wv & 3;
    const int rh = wv >> 2;
    const int row0 = rq * 32 + rh * 16;
    const int colb = gw * 512 + ut * 16;
    const int lane = tid & 63;
    const int n = lane & 15;
    const int q = lane >> 4;
    const int gtid = g * NTHR + tid;

    // ---------------- P0: stage everything ----------------
    h0hi[gtid] = 0; h0lo[gtid] = 0; h1hi[gtid] = 0; h1lo[gtid] = 0;
    stage_split(W0hi, W0lo, whh0, G4 * Hn, gtid, isbf);
    stage_split(W1hi, W1lo, whh1, G4 * Hn, gtid, isbf);
    stage_split(Wi1hi, Wi1lo, wih1, G4 * Hn, gtid, isbf);
    stage(zf, z, Bn * Ln, gtid, isbf);
    stage(cw1f, cw1, Ln * Hn, gtid, isbf);
    stage(cw2f, cw2, Hn * Hn, gtid, isbf);
    stage(cpar + 0, cg1, 512, gtid, isbf);
    stage(cpar + 512, cbeta1, 512, gtid, isbf);
    stage(cpar + 1024, cg2, 512, gtid, isbf);
    stage(cpar + 1536, cbeta2, 512, gtid, isbf);
    stage(cpar + 2048, bo1, 256, gtid, isbf);
    stage(cpar + 2304, bo2, 2, gtid, isbf);
    stage(cpar + 2560, cb2, 512, gtid, isbf);
    stage(cpar + 3072, cb1, 512, gtid, isbf);
    stage(cpar + 3584, wo2, 256 * 2, gtid, isbf);
    stage(wo1f, wo1, Hn * 256, gtid, isbf);
    if (isbf) {
        if (gtid < 256) prevb[gtid] = bf2f(((const u16*)init_t)[gtid & 1]);
        if (gtid < G4) b1sum[gtid] = bf2f(((const u16*)bih1)[gtid]) + bf2f(((const u16*)bhh1)[gtid]);
        if (gtid < G4) bias0f[gtid] = bf2f(((const u16*)bih0)[gtid]) + bf2f(((const u16*)bhh0)[gtid]);
        if (gtid < 4096) {
            size_t ix = (size_t)(gtid >> 1) * 578 + 576 + (gtid & 1);
            wpb[gtid] = bf2f(((const u16*)wih0)[ix]);
        }
    } else {
        if (gtid < 256) prevb[gtid] = ((const float*)init_t)[gtid & 1];
        if (gtid < G4) b1sum[gtid] = ((const float*)bih1)[gtid] + ((const float*)bhh1)[gtid];
        if (gtid < G4) bias0f[gtid] = ((const float*)bih0)[gtid] + ((const float*)bhh0)[gtid];
        if (gtid < 4096) {
            size_t ix = (size_t)(gtid >> 1) * 578 + 576 + (gtid & 1);
            wpb[gtid] = ((const float*)wih0)[ix];
        }
    }
    gbar(bcnt, bgen);
    // ---------------- P1: y1 = z@cw1+cb1 ; build wo1T hi/lo ----------------
    {
        int bb = gtid >> 9, nn = gtid & 511;
        float a = cpar[3072 + nn];
        const float* zr = zf + bb * Ln;
        for (int k = 0; k < Ln; ++k) a += zr[k] * cw1f[k * Hn + nn];
        ybuf[gtid] = a;
    }
    for (int e = gtid; e < 256 * Hn; e += NALL) {
        int nn = e >> 9, kk = e & 511;
        float w = wo1f[kk * 256 + nn];
        u16 hv = f2bf(w);
        wo1Th[e] = hv;
        wo1Tl[e] = f2bf(w - bf2f(hv));
    }
    gbar(bcnt, bgen);
    // ---------------- P2: LN1 + leaky ----------------
    ln_leaky_row(ybuf + g * Hn, cpar + 0, cpar + 512, condf + g * Hn, red);
    gbar(bcnt, bgen);
    // ---------------- P3: y2 = cond1@cw2+cb2 ----------------
    {
        float a = cpar[2560 + tid];
        const float* crow = condf + g * Hn;
        for (int k = 0; k < Hn; ++k) a += crow[k] * cw2f[k * Hn + tid];
        ybuf[g * Hn + tid] = a;
    }
    gbar(bcnt, bgen);
    // ---------------- P4: LN2 + leaky ----------------
    ln_leaky_row(ybuf + g * Hn, cpar + 1024, cpar + 1536, condf + g * Hn, red);
    gbar(bcnt, bgen);
    // ---------------- P5: base0 / embW (fp32; overwrites wo1f temp) ----------
    if (isbf) phase5<true>(wih0, emb, condf, bias0f, base0, embW, gtid);
    else phase5<false>(wih0, emb, condf, bias0f, base0, embW, gtid);
    gbar(bcnt, bgen);

    // ---------------- main loop ----------------
    float c0 = 0.f, c1 = 0.f;
    f32x4 acc1 = {0.f, 0.f, 0.f, 0.f};
    const int p = tid;
    const int rl = p >> 4, ul = p & 15;
    const int bb = 32 * rq + rl;
    const int uu = 16 * ut + ul;
    const float* bo1f = cpar + 2048;
    const float* bo2f = cpar + 2304;
    const float* wo2f = cpar + 3584;

    for (int t = 0; t < Tn; ++t) {
        // ---- X: head(t-1) + recurrent MFMAs (h0@whh0, h1@whh1) ----
        if (wv == 0 && t >= 1)
            head_phase(t - 1, t, g, h1hi, h1lo, wo1Th, wo1Tl, bo1f, wo2f, bo2f,
                       head1f, prevb, outp, isbf, headcnt);
        f32x4 acc0 = mfma_tile3(h0hi, h0lo, Hn, W0hi, W0lo, Hn, row0, colb, Hn);
        acc1 = mfma_tile3(h1hi, h1lo, Hn, W1hi, W1lo, Hn, row0, colb, Hn);
        gbar(bcnt, bgen);

        // ---- Y: gates0 -> h0' ----
#pragma unroll
        for (int r = 0; r < 4; ++r)
            smem[gw * 512 + (rh * 16 + q * 4 + r) * 16 + n] = acc0[r];
        __syncthreads();
        {
            int id = char_ids[bb * Tn + t];
            float pv0 = prevb[2 * bb], pv1 = prevb[2 * bb + 1];
            float gv[4];
#pragma unroll
            for (int gi = 0; gi < 4; ++gi) {
                int cc = gi * 512 + uu;
                gv[gi] = smem[gi * 512 + p] + base0[(size_t)bb * G4 + cc] +
                         embW[(size_t)id * G4 + cc] + pv0 * wpb[2 * cc] + pv1 * wpb[2 * cc + 1];
            }
            float ig = sigm(gv[0]), fg = sigm(gv[1]), gg = tanhf(gv[2]), og = sigm(gv[3]);
            c0 = fg * c0 + ig * gg;
            float h = og * tanhf(c0);
            u16 hv = f2bf(h);
            h0hi[bb * Hn + uu] = hv;
            h0lo[bb * Hn + uu] = f2bf(h - bf2f(hv));
        }
        gbar(bcnt, bgen);

        // ---- Z: gates1 -> h1' ----
        acc1 = acc1 + mfma_tile3(h0hi, h0lo, Hn, Wi1hi, Wi1lo, Hn, row0, colb, Hn);
#pragma unroll
        for (int r = 0; r < 4; ++r)
            smem[gw * 512 + (rh * 16 + q * 4 + r) * 16 + n] = acc1[r];
        __syncthreads();
        {
            float gv[4];
#pragma unroll
            for (int gi = 0; gi < 4; ++gi) {
                int cc = gi * 512 + uu;
                gv[gi] = smem[gi * 512 + p] + b1sum[cc];
            }
            float ig = sigm(gv[0]), fg = sigm(gv[1]), gg = tanhf(gv[2]), og = sigm(gv[3]);
            c1 = fg * c1 + ig * gg;
            float h = og * tanhf(c1);
            u16 hv = f2bf(h);
            h1hi[bb * Hn + uu] = hv;
            h1lo[bb * Hn + uu] = f2bf(h - bf2f(hv));
        }
        gbar(bcnt, bgen);
    }

    // final head for t = 511
    if (wv == 0)
        head_phase(Tn - 1, Tn, g, h1hi, h1lo, wo1Th, wo1Tl, bo1f, wo2f, bo2f,
                   head1f, prevb, outp, isbf, headcnt);
}

extern "C" void kernel_launch(void* const* d_in, const int* in_sizes, int n_in,
                              void* d_out, int out_size, void* d_ws, size_t ws_size,
                              hipStream_t stream) {
    (void)in_sizes; (void)n_in; (void)out_size; (void)ws_size;
    init_flags_kernel<<<1, 64, 0, stream>>>((int*)d_ws);
    gen_kernel<<<WGS, NTHR, 0, stream>>>(
        (const int*)d_in[0], d_in[1], d_in[2], d_in[3], d_in[4], d_in[5], d_in[6], d_in[7],
        d_in[8], d_in[9], d_in[10], d_in[11], d_in[12], d_in[13], d_in[14], d_in[15], d_in[16],
        d_in[17], d_in[18], d_in[19], d_in[20], d_in[21], d_in[22], d_in[23],
        d_out, (char*)d_ws);
}

// Round 4
// 41745.920 us; speedup vs baseline: 1.5347x; 1.5347x over previous
//
#include <hip/hip_runtime.h>

// Problem constants
#define Bn 128
#define Tn 512
#define Vn 128
#define En 64
#define Ln 128
#define Hn 512
#define G4 2048
#define WGS 128
#define NTHR 512
#define NALL 65536
#define LSTR 160  // LDS row stride in u16 (320B: 16B-aligned, 2-way-bank-free b128 reads)

typedef unsigned short u16;
typedef unsigned int u32;
typedef __bf16 bf16x8 __attribute__((ext_vector_type(8)));
typedef float f32x4 __attribute__((ext_vector_type(4)));

__device__ inline float bf2f(u16 h) {
    u32 u = ((u32)h) << 16;
    float f;
    __builtin_memcpy(&f, &u, 4);
    return f;
}
__device__ inline u16 f2bf(float f) {
    u32 u;
    __builtin_memcpy(&u, &f, 4);
    u32 r = (u + 0x7fffu + ((u >> 16) & 1u)) >> 16;
    return (u16)r;
}
__device__ inline u32 f2u(float f) { u32 u; __builtin_memcpy(&u, &f, 4); return u; }
__device__ inline float u2f(u32 u) { float f; __builtin_memcpy(&f, &u, 4); return f; }
__device__ inline float sigm(float x) { return 1.f / (1.f + expf(-x)); }
__device__ inline float leaky(float x) { return x > 0.f ? x : 0.2f * x; }
__device__ inline float softplus(float x) {
    return x > 0.f ? x + log1pf(expf(-x)) : log1pf(expf(x));
}

// relaxed agent-coherent accessors (bypass non-coherent per-XCD L2)
__device__ inline u32 aload(const u32* p) {
    return __hip_atomic_load(p, __ATOMIC_RELAXED, __HIP_MEMORY_SCOPE_AGENT);
}
__device__ inline void astore(u32* p, u32 v) {
    __hip_atomic_store(p, v, __ATOMIC_RELAXED, __HIP_MEMORY_SCOPE_AGENT);
}
__device__ inline int aload_i(const int* p) {
    return __hip_atomic_load(p, __ATOMIC_RELAXED, __HIP_MEMORY_SCOPE_AGENT);
}

// Workspace layout (bytes); total ~17 MB
#define OFF_FLAGS  0x000000   // 1024 ints: grp g: cnt@64g, gen@64g+16, pseq@64g+32; heavy: cnt@512 gen@528
#define OFF_PREV   0x001000   // 256 u32 (f32 bits)
#define OFF_B1SUM  0x002000
#define OFF_WP     0x004000
#define OFF_BIAS0  0x008000
#define OFF_CPAR   0x00A000   // f32: cg1,cbeta1,cg2,cbeta2; bo1@2048, bo2@2304, cb2@2560, cb1@3072, wo2f@3584
#define OFF_H0P    0x010000   // 128x512 u32 (hi|lo<<16)
#define OFF_H1P    0x050000
#define OFF_HEAD1F 0x090000   // 128x256 u32 (f32 bits)
#define OFF_WO1TH  0x0B0000   // 256x512 bf16
#define OFF_WO1TL  0x0F0000
#define OFF_ZF     0x130000
#define OFF_CW1F   0x140000
#define OFF_CW2F   0x180000
#define OFF_CONDF  0x280000
#define OFF_YBUF   0x2C0000
#define OFF_BASE0  0x300000   // 1MB f32 (temp: wo1f in P0/P1)
#define OFF_EMBW   0x400000
#define OFF_W0HI   0x500000   // 2048x512 bf16 each
#define OFF_W0LO   0x700000
#define OFF_W1HI   0x900000
#define OFF_W1LO   0xB00000
#define OFF_WI1HI  0xD00000
#define OFF_WI1LO  0xF00000   // end 0x1100000

// heavy grid barrier (pre-phase only: full flush semantics, 128 WGs)
__device__ inline void gbar_heavy(int* cnt, int* gen) {
    __syncthreads();
    if (threadIdx.x == 0) {
        __threadfence();
        int g = __hip_atomic_load(gen, __ATOMIC_RELAXED, __HIP_MEMORY_SCOPE_AGENT);
        int arrived = __hip_atomic_fetch_add(cnt, 1, __ATOMIC_ACQ_REL, __HIP_MEMORY_SCOPE_AGENT);
        if (arrived == WGS - 1) {
            __hip_atomic_store(cnt, 0, __ATOMIC_RELAXED, __HIP_MEMORY_SCOPE_AGENT);
            __hip_atomic_store(gen, g + 1, __ATOMIC_RELEASE, __HIP_MEMORY_SCOPE_AGENT);
        } else {
            while (__hip_atomic_load(gen, __ATOMIC_ACQUIRE, __HIP_MEMORY_SCOPE_AGENT) == g)
                __builtin_amdgcn_s_sleep(1);
        }
        __threadfence();
    }
    __syncthreads();
}

// light group barrier: relaxed spin, release arrival (drains h-stores), no cache flush
__device__ inline void gbar_light(int* cnt, int* gen, int members) {
    __syncthreads();
    if (threadIdx.x == 0) {
        int g = __hip_atomic_load(gen, __ATOMIC_RELAXED, __HIP_MEMORY_SCOPE_AGENT);
        int arrived = __hip_atomic_fetch_add(cnt, 1, __ATOMIC_RELEASE, __HIP_MEMORY_SCOPE_AGENT);
        if (arrived == members - 1) {
            __hip_atomic_store(cnt, 0, __ATOMIC_RELAXED, __HIP_MEMORY_SCOPE_AGENT);
            __hip_atomic_store(gen, g + 1, __ATOMIC_RELEASE, __HIP_MEMORY_SCOPE_AGENT);
        } else {
            while (__hip_atomic_load(gen, __ATOMIC_RELAXED, __HIP_MEMORY_SCOPE_AGENT) == g)
                __builtin_amdgcn_s_sleep(2);
        }
    }
    __syncthreads();
}

__device__ inline void unpack8(const u32* w, bf16x8& ah, bf16x8& al) {
    u32 hs[4], ls[4];
#pragma unroll
    for (int j = 0; j < 4; ++j) {
        hs[j] = (w[2 * j] & 0xFFFFu) | (w[2 * j + 1] << 16);
        ls[j] = (w[2 * j] >> 16) | (w[2 * j + 1] & 0xFFFF0000u);
    }
    __builtin_memcpy(&ah, hs, 16);
    __builtin_memcpy(&al, ls, 16);
}

// dtype-safe staging
__device__ inline void stage(float* dst, const void* src, int n, int gtid, bool isbf) {
    if (isbf) {
        const u16* s = (const u16*)src;
        for (int e = gtid; e < n; e += NALL) dst[e] = bf2f(s[e]);
    } else {
        const float* s = (const float*)src;
        for (int e = gtid; e < n; e += NALL) dst[e] = s[e];
    }
}
__device__ inline void stage_split(u16* hi, u16* lo, const void* src, int n, int gtid, bool isbf) {
    if (isbf) {
        const u16* s = (const u16*)src;
        for (int e = gtid; e < n; e += NALL) { hi[e] = s[e]; lo[e] = 0; }
    } else {
        const float* s = (const float*)src;
        for (int e = gtid; e < n; e += NALL) {
            float w = s[e];
            u16 h = f2bf(w);
            hi[e] = h;
            lo[e] = f2bf(w - bf2f(h));
        }
    }
}

template <bool ISBF>
__device__ inline float ldw(const void* p, size_t i) {
    if constexpr (ISBF) return bf2f(((const u16*)p)[i]);
    else return ((const float*)p)[i];
}

template <bool ISBF>
__device__ void phase5(const void* wih0, const void* emb, const float* __restrict__ condf,
                       const float* __restrict__ bias0f, float* __restrict__ base0,
                       float* __restrict__ embW, int gtid) {
    const int cc = gtid & 2047;
    const int bb0 = gtid >> 11;
    float b = bias0f[cc];
    float a0 = b, a1 = b, a2 = b, a3 = b;
    const float* c0p = condf + (size_t)bb0 * Hn;
    const float* c1p = condf + (size_t)(bb0 + 32) * Hn;
    const float* c2p = condf + (size_t)(bb0 + 64) * Hn;
    const float* c3p = condf + (size_t)(bb0 + 96) * Hn;
    const size_t wb = (size_t)cc * 578 + 64;
    for (int k = 0; k < Hn; ++k) {
        float w = ldw<ISBF>(wih0, wb + k);
        a0 += c0p[k] * w; a1 += c1p[k] * w; a2 += c2p[k] * w; a3 += c3p[k] * w;
    }
    base0[(size_t)bb0 * G4 + cc] = a0;
    base0[(size_t)(bb0 + 32) * G4 + cc] = a1;
    base0[(size_t)(bb0 + 64) * G4 + cc] = a2;
    base0[(size_t)(bb0 + 96) * G4 + cc] = a3;
    float e0 = 0.f, e1 = 0.f, e2 = 0.f, e3 = 0.f;
    const size_t wb2 = (size_t)cc * 578;
    for (int k = 0; k < En; ++k) {
        float w = ldw<ISBF>(wih0, wb2 + k);
        e0 += ldw<ISBF>(emb, (size_t)bb0 * En + k) * w;
        e1 += ldw<ISBF>(emb, (size_t)(bb0 + 32) * En + k) * w;
        e2 += ldw<ISBF>(emb, (size_t)(bb0 + 64) * En + k) * w;
        e3 += ldw<ISBF>(emb, (size_t)(bb0 + 96) * En + k) * w;
    }
    embW[(size_t)bb0 * G4 + cc] = e0;
    embW[(size_t)(bb0 + 32) * G4 + cc] = e1;
    embW[(size_t)(bb0 + 64) * G4 + cc] = e2;
    embW[(size_t)(bb0 + 96) * G4 + cc] = e3;
}

__device__ inline void ln_leaky_row(const float* __restrict__ x, const float* __restrict__ gamma,
                                    const float* __restrict__ beta, float* __restrict__ out,
                                    float* red) {
    int tid = threadIdx.x;
    float v = x[tid];
    float s = v, s2 = v * v;
    for (int off = 32; off; off >>= 1) {
        s += __shfl_down(s, off);
        s2 += __shfl_down(s2, off);
    }
    int wv = tid >> 6;
    if ((tid & 63) == 0) { red[wv * 2] = s; red[wv * 2 + 1] = s2; }
    __syncthreads();
    if (tid == 0) {
        float ts = 0.f, ts2 = 0.f;
        for (int i = 0; i < 8; ++i) { ts += red[i * 2]; ts2 += red[i * 2 + 1]; }
        float m = ts / 512.f;
        float var = ts2 / 512.f - m * m;
        red[16] = m;
        red[17] = rsqrtf(var + 1e-5f);
    }
    __syncthreads();
    float m = red[16], rs = red[17];
    out[tid] = leaky((v - m) * rs * gamma[tid] + beta[tid]);
    __syncthreads();
}

// head1: one 16x16 tile per WG within its group (wave 0 only)
__device__ inline void head1_part(int rq, int ut, const u32* __restrict__ h1p,
                                  const u16* __restrict__ wo1Th, const u16* __restrict__ wo1Tl,
                                  const float* __restrict__ bo1f, u32* __restrict__ head1f) {
    const int lane = threadIdx.x & 63;
    const int n = lane & 15, q = lane >> 4;
    const int r0 = rq * 32 + (ut >> 4) * 16;
    const int c0 = (ut & 15) * 16;
    f32x4 a1 = {0.f, 0.f, 0.f, 0.f}, a2 = a1, a3 = a1;
    const u32* ap = h1p + (size_t)(r0 + n) * Hn;
    const u16* bh = wo1Th + (size_t)(c0 + n) * Hn;
    const u16* bl = wo1Tl + (size_t)(c0 + n) * Hn;
    for (int k = 0; k < Hn; k += 32) {
        const int kb = k + q * 8;
        u32 w[8];
#pragma unroll
        for (int i = 0; i < 8; ++i) w[i] = aload(ap + kb + i);
        bf16x8 ah, al;
        unpack8(w, ah, al);
        bf16x8 vbh = *reinterpret_cast<const bf16x8*>(bh + kb);
        bf16x8 vbl = *reinterpret_cast<const bf16x8*>(bl + kb);
        a1 = __builtin_amdgcn_mfma_f32_16x16x32_bf16(ah, vbh, a1, 0, 0, 0);
        a2 = __builtin_amdgcn_mfma_f32_16x16x32_bf16(al, vbh, a2, 0, 0, 0);
        a3 = __builtin_amdgcn_mfma_f32_16x16x32_bf16(ah, vbl, a3, 0, 0, 0);
    }
    f32x4 a = a1 + a2 + a3;
#pragma unroll
    for (int r = 0; r < 4; ++r) {
        int cc = c0 + n;
        astore(head1f + (r0 + q * 4 + r) * 256 + cc, f2u(leaky(a[r] + bo1f[cc])));
    }
}

// head2: 32 rows x 2 outputs for this group (one wave)
__device__ inline void head2_part(int tt, int rq, const u32* __restrict__ head1f,
                                  const float* __restrict__ wo2f, const float* __restrict__ bo2f,
                                  u32* __restrict__ prevb, int* pseq, void* outp, bool isbf) {
    const int lane = threadIdx.x & 63;
    const int row = rq * 32 + (lane >> 1), j = lane & 1;
    float s = bo2f[j];
    const u32* hr = head1f + row * 256;
#pragma unroll 8
    for (int k = 0; k < 256; ++k) s += u2f(aload(hr + k)) * wo2f[k * 2 + j];
    float y = softplus(s) + 0.005f;
    astore(prevb + row * 2 + j, f2u(y));
    size_t oi = ((size_t)row * Tn + tt) * 2 + j;
    if (isbf) ((u16*)outp)[oi] = f2bf(y);
    else ((float*)outp)[oi] = y;
    __builtin_amdgcn_s_waitcnt(0);
    if (lane == 0)
        __hip_atomic_store(pseq, tt + 1, __ATOMIC_RELEASE, __HIP_MEMORY_SCOPE_AGENT);
}

__global__ void init_flags_kernel(int* flags) { flags[threadIdx.x] = 0; }

__global__ __launch_bounds__(NTHR, 1) void gen_kernel(
    const int* __restrict__ char_ids, const void* z, const void* emb,
    const void* cw1, const void* cb1, const void* cg1, const void* cbeta1,
    const void* cw2, const void* cb2, const void* cg2, const void* cbeta2,
    const void* wih0, const void* whh0, const void* bih0, const void* bhh0,
    const void* wih1, const void* whh1, const void* bih1, const void* bhh1,
    const void* wo1, const void* bo1, const void* wo2, const void* bo2,
    const void* init_t, void* outp, char* __restrict__ ws) {
    __shared__ char LDSb[40960];   // 4 planes of 32xLSTR u16 (staging) / aliased f32 exchange
    __shared__ float red[34];
    u16* lh0h = (u16*)LDSb;
    u16* lh0l = (u16*)(LDSb + 10240);
    u16* lh1h = (u16*)(LDSb + 20480);
    u16* lh1l = (u16*)(LDSb + 30720);
    float* smemf = (float*)LDSb;

    int* flags = (int*)(ws + OFF_FLAGS);
    u32* prevb = (u32*)(ws + OFF_PREV);
    float* b1sum = (float*)(ws + OFF_B1SUM);
    float* wpb = (float*)(ws + OFF_WP);
    float* bias0f = (float*)(ws + OFF_BIAS0);
    float* cpar = (float*)(ws + OFF_CPAR);
    u32* h0p = (u32*)(ws + OFF_H0P);
    u32* h1p = (u32*)(ws + OFF_H1P);
    u32* head1f = (u32*)(ws + OFF_HEAD1F);
    u16* wo1Th = (u16*)(ws + OFF_WO1TH);
    u16* wo1Tl = (u16*)(ws + OFF_WO1TL);
    float* zf = (float*)(ws + OFF_ZF);
    float* cw1f = (float*)(ws + OFF_CW1F);
    float* cw2f = (float*)(ws + OFF_CW2F);
    float* condf = (float*)(ws + OFF_CONDF);
    float* ybuf = (float*)(ws + OFF_YBUF);
    float* base0 = (float*)(ws + OFF_BASE0);
    float* embW = (float*)(ws + OFF_EMBW);
    u16* W0hi = (u16*)(ws + OFF_W0HI);
    u16* W0lo = (u16*)(ws + OFF_W0LO);
    u16* W1hi = (u16*)(ws + OFF_W1HI);
    u16* W1lo = (u16*)(ws + OFF_W1LO);
    u16* Wi1hi = (u16*)(ws + OFF_WI1HI);
    u16* Wi1lo = (u16*)(ws + OFF_WI1LO);
    float* wo1f = base0;  // temp until P5

    const bool isbf = (((const u32*)cg1)[0] == 0x3F803F80u);

    const int g = blockIdx.x;
    const int tid = threadIdx.x;
    const int wv = tid >> 6;
    const int rq = g >> 5;      // batch-quadrant group (32 WGs)
    const int ut = g & 31;      // unit block
    const int gw = wv & 3;      // gate
    const int rh = wv >> 2;     // row half
    const int R0g = rq * 32;
    const int row0l = rh * 16;  // local row base within group's 32 rows
    const int colb = gw * 512 + ut * 16;
    const int lane = tid & 63;
    const int n = lane & 15;
    const int q = lane >> 4;
    const int gtid = g * NTHR + tid;
    const f32x4 Z4 = {0.f, 0.f, 0.f, 0.f};

    int* gcnt = flags + 64 * rq;
    int* ggen = flags + 64 * rq + 16;
    int* pseq = flags + 64 * rq + 32;
    int* hcnt = flags + 512;
    int* hgen = flags + 528;

    // ---------------- P0: stage everything ----------------
    h0p[gtid] = 0;
    h1p[gtid] = 0;
    stage_split(W0hi, W0lo, whh0, G4 * Hn, gtid, isbf);
    stage_split(W1hi, W1lo, whh1, G4 * Hn, gtid, isbf);
    stage_split(Wi1hi, Wi1lo, wih1, G4 * Hn, gtid, isbf);
    stage(zf, z, Bn * Ln, gtid, isbf);
    stage(cw1f, cw1, Ln * Hn, gtid, isbf);
    stage(cw2f, cw2, Hn * Hn, gtid, isbf);
    stage(cpar + 0, cg1, 512, gtid, isbf);
    stage(cpar + 512, cbeta1, 512, gtid, isbf);
    stage(cpar + 1024, cg2, 512, gtid, isbf);
    stage(cpar + 1536, cbeta2, 512, gtid, isbf);
    stage(cpar + 2048, bo1, 256, gtid, isbf);
    stage(cpar + 2304, bo2, 2, gtid, isbf);
    stage(cpar + 2560, cb2, 512, gtid, isbf);
    stage(cpar + 3072, cb1, 512, gtid, isbf);
    stage(cpar + 3584, wo2, 256 * 2, gtid, isbf);
    stage(wo1f, wo1, Hn * 256, gtid, isbf);
    if (isbf) {
        if (gtid < 256) prevb[gtid] = f2u(bf2f(((const u16*)init_t)[gtid & 1]));
        if (gtid < G4) b1sum[gtid] = bf2f(((const u16*)bih1)[gtid]) + bf2f(((const u16*)bhh1)[gtid]);
        if (gtid < G4) bias0f[gtid] = bf2f(((const u16*)bih0)[gtid]) + bf2f(((const u16*)bhh0)[gtid]);
        if (gtid < 4096) {
            size_t ix = (size_t)(gtid >> 1) * 578 + 576 + (gtid & 1);
            wpb[gtid] = bf2f(((const u16*)wih0)[ix]);
        }
    } else {
        if (gtid < 256) prevb[gtid] = f2u(((const float*)init_t)[gtid & 1]);
        if (gtid < G4) b1sum[gtid] = ((const float*)bih1)[gtid] + ((const float*)bhh1)[gtid];
        if (gtid < G4) bias0f[gtid] = ((const float*)bih0)[gtid] + ((const float*)bhh0)[gtid];
        if (gtid < 4096) {
            size_t ix = (size_t)(gtid >> 1) * 578 + 576 + (gtid & 1);
            wpb[gtid] = ((const float*)wih0)[ix];
        }
    }
    gbar_heavy(hcnt, hgen);
    // ---------------- P1: y1 = z@cw1+cb1 ; wo1T hi/lo ----------------
    {
        int bb = gtid >> 9, nn = gtid & 511;
        float a = cpar[3072 + nn];
        const float* zr = zf + bb * Ln;
        for (int k = 0; k < Ln; ++k) a += zr[k] * cw1f[k * Hn + nn];
        ybuf[gtid] = a;
    }
    for (int e = gtid; e < 256 * Hn; e += NALL) {
        int nn = e >> 9, kk = e & 511;
        float w = wo1f[kk * 256 + nn];
        u16 hv = f2bf(w);
        wo1Th[e] = hv;
        wo1Tl[e] = f2bf(w - bf2f(hv));
    }
    gbar_heavy(hcnt, hgen);
    ln_leaky_row(ybuf + g * Hn, cpar + 0, cpar + 512, condf + g * Hn, red);
    gbar_heavy(hcnt, hgen);
    {
        float a = cpar[2560 + tid];
        const float* crow = condf + g * Hn;
        for (int k = 0; k < Hn; ++k) a += crow[k] * cw2f[k * Hn + tid];
        ybuf[g * Hn + tid] = a;
    }
    gbar_heavy(hcnt, hgen);
    ln_leaky_row(ybuf + g * Hn, cpar + 1024, cpar + 1536, condf + g * Hn, red);
    gbar_heavy(hcnt, hgen);
    if (isbf) phase5<true>(wih0, emb, condf, bias0f, base0, embW, gtid);
    else phase5<false>(wih0, emb, condf, bias0f, base0, embW, gtid);
    gbar_heavy(hcnt, hgen);   // flushes all pre-phase writes device-wide

    // ---------------- main loop ----------------
    float c0 = 0.f, c1 = 0.f;
    const int p = tid;
    const int bb = R0g + (p >> 4);
    const int uu = ut * 16 + (p & 15);
    const float* bo1f = cpar + 2048;
    const float* bo2f = cpar + 2304;
    const float* wo2f = cpar + 3584;
    const int srow = tid >> 4;        // 0..31 staging row
    const int sks = (tid & 15) * 8;   // staging k-slot

    f32x4 acc1 = Z4;

    for (int t = 0; t < Tn; ++t) {
        // ---- X: stage h0,h1 (t-1) through LDS, MFMA whh0/whh1; head1(t-1) by wave0 ----
        f32x4 x0a = Z4, x0b = Z4, x0c = Z4, x1a = Z4, x1b = Z4, x1c = Z4;
        for (int c = 0; c < 4; ++c) {
            __syncthreads();
            u32 w0[8], w1[8];
            const u32* g0 = h0p + (size_t)(R0g + srow) * Hn + c * 128 + sks;
            const u32* g1 = h1p + (size_t)(R0g + srow) * Hn + c * 128 + sks;
#pragma unroll
            for (int i = 0; i < 8; ++i) w0[i] = aload(g0 + i);
#pragma unroll
            for (int i = 0; i < 8; ++i) w1[i] = aload(g1 + i);
            u32* d0h = (u32*)(lh0h + srow * LSTR + sks);
            u32* d0l = (u32*)(lh0l + srow * LSTR + sks);
            u32* d1h = (u32*)(lh1h + srow * LSTR + sks);
            u32* d1l = (u32*)(lh1l + srow * LSTR + sks);
#pragma unroll
            for (int j = 0; j < 4; ++j) {
                d0h[j] = (w0[2 * j] & 0xFFFFu) | (w0[2 * j + 1] << 16);
                d0l[j] = (w0[2 * j] >> 16) | (w0[2 * j + 1] & 0xFFFF0000u);
                d1h[j] = (w1[2 * j] & 0xFFFFu) | (w1[2 * j + 1] << 16);
                d1l[j] = (w1[2 * j] >> 16) | (w1[2 * j + 1] & 0xFFFF0000u);
            }
            __syncthreads();
#pragma unroll
            for (int it = 0; it < 4; ++it) {
                const int ko = it * 32 + q * 8;
                const int lrow = (row0l + n) * LSTR + ko;
                bf16x8 a0h = *reinterpret_cast<const bf16x8*>(lh0h + lrow);
                bf16x8 a0l = *reinterpret_cast<const bf16x8*>(lh0l + lrow);
                bf16x8 a1h = *reinterpret_cast<const bf16x8*>(lh1h + lrow);
                bf16x8 a1l = *reinterpret_cast<const bf16x8*>(lh1l + lrow);
                const size_t wb = (size_t)(colb + n) * Hn + c * 128 + ko;
                bf16x8 b0h = *reinterpret_cast<const bf16x8*>(W0hi + wb);
                bf16x8 b0l = *reinterpret_cast<const bf16x8*>(W0lo + wb);
                bf16x8 b1h = *reinterpret_cast<const bf16x8*>(W1hi + wb);
                bf16x8 b1l = *reinterpret_cast<const bf16x8*>(W1lo + wb);
                x0a = __builtin_amdgcn_mfma_f32_16x16x32_bf16(a0h, b0h, x0a, 0, 0, 0);
                x0b = __builtin_amdgcn_mfma_f32_16x16x32_bf16(a0l, b0h, x0b, 0, 0, 0);
                x0c = __builtin_amdgcn_mfma_f32_16x16x32_bf16(a0h, b0l, x0c, 0, 0, 0);
                x1a = __builtin_amdgcn_mfma_f32_16x16x32_bf16(a1h, b1h, x1a, 0, 0, 0);
                x1b = __builtin_amdgcn_mfma_f32_16x16x32_bf16(a1l, b1h, x1b, 0, 0, 0);
                x1c = __builtin_amdgcn_mfma_f32_16x16x32_bf16(a1h, b1l, x1c, 0, 0, 0);
            }
        }
        f32x4 acc0 = x0a + x0b + x0c;
        acc1 = x1a + x1b + x1c;
        if (wv == 0 && t >= 1)
            head1_part(rq, ut, h1p, wo1Th, wo1Tl, bo1f, head1f);
        gbar_light(gcnt, ggen, 32);

        // ---- Y: exchange acc0, head2 (group leader wave), gates0 -> h0(t) ----
#pragma unroll
        for (int r = 0; r < 4; ++r)
            smemf[gw * 512 + (rh * 16 + q * 4 + r) * 16 + n] = acc0[r];
        __syncthreads();
        if (ut == 0 && wv == 0 && t >= 1)
            head2_part(t - 1, rq, head1f, wo2f, bo2f, prevb, pseq, outp, isbf);
        while (aload_i(pseq) < t) __builtin_amdgcn_s_sleep(2);
        {
            int id = char_ids[bb * Tn + t];
            float pv0 = u2f(aload(prevb + 2 * bb)), pv1 = u2f(aload(prevb + 2 * bb + 1));
            float gv[4];
#pragma unroll
            for (int gi = 0; gi < 4; ++gi) {
                int cc = gi * 512 + uu;
                gv[gi] = smemf[gi * 512 + p] + base0[(size_t)bb * G4 + cc] +
                         embW[(size_t)id * G4 + cc] + pv0 * wpb[2 * cc] + pv1 * wpb[2 * cc + 1];
            }
            float ig = sigm(gv[0]), fg = sigm(gv[1]), gg = tanhf(gv[2]), og = sigm(gv[3]);
            c0 = fg * c0 + ig * gg;
            float h = og * tanhf(c0);
            u16 hv = f2bf(h);
            u16 lv = f2bf(h - bf2f(hv));
            astore(h0p + (size_t)bb * Hn + uu, (u32)hv | ((u32)lv << 16));
        }
        gbar_light(gcnt, ggen, 32);

        // ---- Z: stage h0(t), MFMA wih1, gates1 -> h1(t) ----
        for (int c = 0; c < 4; ++c) {
            __syncthreads();
            u32 w0[8];
            const u32* g0 = h0p + (size_t)(R0g + srow) * Hn + c * 128 + sks;
#pragma unroll
            for (int i = 0; i < 8; ++i) w0[i] = aload(g0 + i);
            u32* d0h = (u32*)(lh0h + srow * LSTR + sks);
            u32* d0l = (u32*)(lh0l + srow * LSTR + sks);
#pragma unroll
            for (int j = 0; j < 4; ++j) {
                d0h[j] = (w0[2 * j] & 0xFFFFu) | (w0[2 * j + 1] << 16);
                d0l[j] = (w0[2 * j] >> 16) | (w0[2 * j + 1] & 0xFFFF0000u);
            }
            __syncthreads();
#pragma unroll
            for (int it = 0; it < 4; ++it) {
                const int ko = it * 32 + q * 8;
                const int lrow = (row0l + n) * LSTR + ko;
                bf16x8 a0h = *reinterpret_cast<const bf16x8*>(lh0h + lrow);
                bf16x8 a0l = *reinterpret_cast<const bf16x8*>(lh0l + lrow);
                const size_t wb = (size_t)(colb + n) * Hn + c * 128 + ko;
                bf16x8 bh = *reinterpret_cast<const bf16x8*>(Wi1hi + wb);
                bf16x8 bl = *reinterpret_cast<const bf16x8*>(Wi1lo + wb);
                acc1 = __builtin_amdgcn_mfma_f32_16x16x32_bf16(a0h, bh, acc1, 0, 0, 0);
                acc1 = __builtin_amdgcn_mfma_f32_16x16x32_bf16(a0l, bh, acc1, 0, 0, 0);
                acc1 = __builtin_amdgcn_mfma_f32_16x16x32_bf16(a0h, bl, acc1, 0, 0, 0);
            }
        }
        __syncthreads();
#pragma unroll
        for (int r = 0; r < 4; ++r)
            smemf[gw * 512 + (rh * 16 + q * 4 + r) * 16 + n] = acc1[r];
        __syncthreads();
        {
            float gv[4];
#pragma unroll
            for (int gi = 0; gi < 4; ++gi) {
                int cc = gi * 512 + uu;
                gv[gi] = smemf[gi * 512 + p] + b1sum[cc];
            }
            float ig = sigm(gv[0]), fg = sigm(gv[1]), gg = tanhf(gv[2]), og = sigm(gv[3]);
            c1 = fg * c1 + ig * gg;
            float h = og * tanhf(c1);
            u16 hv = f2bf(h);
            u16 lv = f2bf(h - bf2f(hv));
            astore(h1p + (size_t)bb * Hn + uu, (u32)hv | ((u32)lv << 16));
        }
        gbar_light(gcnt, ggen, 32);
    }

    // final head for t = 511
    if (wv == 0)
        head1_part(rq, ut, h1p, wo1Th, wo1Tl, bo1f, head1f);
    gbar_light(gcnt, ggen, 32);
    if (ut == 0 && wv == 0)
        head2_part(Tn - 1, rq, head1f, wo2f, bo2f, prevb, pseq, outp, isbf);
}

extern "C" void kernel_launch(void* const* d_in, const int* in_sizes, int n_in,
                              void* d_out, int out_size, void* d_ws, size_t ws_size,
                              hipStream_t stream) {
    (void)in_sizes; (void)n_in; (void)out_size; (void)ws_size;
    init_flags_kernel<<<1, 1024, 0, stream>>>((int*)d_ws);
    gen_kernel<<<WGS, NTHR, 0, stream>>>(
        (const int*)d_in[0], d_in[1], d_in[2], d_in[3], d_in[4], d_in[5], d_in[6], d_in[7],
        d_in[8], d_in[9], d_in[10], d_in[11], d_in[12], d_in[13], d_in[14], d_in[15], d_in[16],
        d_in[17], d_in[18], d_in[19], d_in[20], d_in[21], d_in[22], d_in[23],
        d_out, (char*)d_ws);
}

// Round 6
// 23095.212 us; speedup vs baseline: 2.7740x; 1.8076x over previous
//
#include <hip/hip_runtime.h>

// Problem constants
#define Bn 128
#define Tn 512
#define Vn 128
#define En 64
#define Ln 128
#define Hn 512
#define G4 2048
#define WGS 128
#define NTHR 512
#define NALL 65536
#define LSTR 520  // LDS row stride in u16; 260 dwords = 4 mod 32 -> spread banks for b128

typedef unsigned short u16;
typedef unsigned int u32;
typedef __bf16 bf16x8 __attribute__((ext_vector_type(8)));
typedef float f32x4 __attribute__((ext_vector_type(4)));
typedef u32 u32x4 __attribute__((ext_vector_type(4)));

__device__ inline float bf2f(u16 h) {
    u32 u = ((u32)h) << 16;
    float f;
    __builtin_memcpy(&f, &u, 4);
    return f;
}
__device__ inline u16 f2bf(float f) {
    u32 u;
    __builtin_memcpy(&u, &f, 4);
    u32 r = (u + 0x7fffu + ((u >> 16) & 1u)) >> 16;
    return (u16)r;
}
__device__ inline u32 f2u(float f) { u32 u; __builtin_memcpy(&u, &f, 4); return u; }
__device__ inline float u2f(u32 u) { float f; __builtin_memcpy(&f, &u, 4); return f; }
__device__ inline float sigm(float x) { return 1.f / (1.f + expf(-x)); }
__device__ inline float leaky(float x) { return x > 0.f ? x : 0.2f * x; }
__device__ inline float softplus(float x) {
    return x > 0.f ? x + log1pf(expf(-x)) : log1pf(expf(x));
}

// ---- coherent (device-scope, L2-bypass) vector memory ops ----
// 16 dwords from p; the s_waitcnt lives INSIDE the asm so the compiler cannot
// schedule consumers of the outputs before the wait (round-5 NaN bug).
__device__ inline void cload16(const u32* p, u32* w) {
    u32x4 v0, v1, v2, v3;
    asm volatile(
        "global_load_dwordx4 %0, %4, off sc0 sc1\n\t"
        "global_load_dwordx4 %1, %4, off offset:16 sc0 sc1\n\t"
        "global_load_dwordx4 %2, %4, off offset:32 sc0 sc1\n\t"
        "global_load_dwordx4 %3, %4, off offset:48 sc0 sc1\n\t"
        "s_waitcnt vmcnt(0)"
        : "=&v"(v0), "=&v"(v1), "=&v"(v2), "=&v"(v3)
        : "v"(p)
        : "memory");
    *(u32x4*)(w) = v0;
    *(u32x4*)(w + 4) = v1;
    *(u32x4*)(w + 8) = v2;
    *(u32x4*)(w + 12) = v3;
}
__device__ inline void cwait() { asm volatile("s_waitcnt vmcnt(0)" ::: "memory"); }
__device__ inline void cstore1(u32* p, u32 v) {
    asm volatile("global_store_dword %0, %1, off sc0 sc1" :: "v"(p), "v"(v) : "memory");
}
__device__ inline void cstoref(float* p, float v) { cstore1((u32*)p, f2u(v)); }

// Workspace layout (bytes)
#define OFF_FLAGS  0x000000   // 1024 ints: grp g: cnt@64g, gen@64g+16; heavy: cnt@512 gen@528
#define OFF_B1SUM  0x002000
#define OFF_WP     0x004000
#define OFF_BIAS0  0x008000
#define OFF_CPAR   0x00A000   // f32: cg1,cbeta1,cg2,cbeta2; bo1@2048, bo2@2304, cb2@2560, cb1@3072, wo2f@3584
#define OFF_H0P    0x010000   // 128x512 u32 (hi|lo<<16)
#define OFF_H1P    0x050000
#define OFF_HEAD1F 0x090000   // 128x256 f32
#define OFF_WO1TH  0x0B0000   // 256x512 bf16
#define OFF_WO1TL  0x0F0000
#define OFF_ZF     0x130000
#define OFF_CW1F   0x140000
#define OFF_CW2F   0x180000
#define OFF_CONDF  0x280000
#define OFF_YBUF   0x2C0000
#define OFF_BASE0  0x300000   // 1MB f32 (temp: wo1f in P0/P1)
#define OFF_EMBW   0x400000
#define OFF_W0HI   0x500000   // 2048x512 bf16 each
#define OFF_W0LO   0x700000
#define OFF_W1HI   0x900000
#define OFF_W1LO   0xB00000
#define OFF_WI1HI  0xD00000
#define OFF_WI1LO  0xF00000   // end 0x1100000

// heavy grid barrier (pre-phase only: acquire invalidates L2, release writes back)
__device__ inline void gbar_heavy(int* cnt, int* gen) {
    __syncthreads();
    if (threadIdx.x == 0) {
        __threadfence();
        int g = __hip_atomic_load(gen, __ATOMIC_RELAXED, __HIP_MEMORY_SCOPE_AGENT);
        int arrived = __hip_atomic_fetch_add(cnt, 1, __ATOMIC_ACQ_REL, __HIP_MEMORY_SCOPE_AGENT);
        if (arrived == WGS - 1) {
            __hip_atomic_store(cnt, 0, __ATOMIC_RELAXED, __HIP_MEMORY_SCOPE_AGENT);
            __hip_atomic_store(gen, g + 1, __ATOMIC_RELEASE, __HIP_MEMORY_SCOPE_AGENT);
        } else {
            while (__hip_atomic_load(gen, __ATOMIC_ACQUIRE, __HIP_MEMORY_SCOPE_AGENT) == g)
                __builtin_amdgcn_s_sleep(1);
        }
        __threadfence();
    }
    __syncthreads();
}

// light group barrier: per-wave vmcnt drain + relaxed spin (no cache flush/invalidate)
__device__ inline void gbar_light(int* cnt, int* gen, int members) {
    cwait();
    __syncthreads();
    if (threadIdx.x == 0) {
        int g = __hip_atomic_load(gen, __ATOMIC_RELAXED, __HIP_MEMORY_SCOPE_AGENT);
        int arrived = __hip_atomic_fetch_add(cnt, 1, __ATOMIC_RELEASE, __HIP_MEMORY_SCOPE_AGENT);
        if (arrived == members - 1) {
            __hip_atomic_store(cnt, 0, __ATOMIC_RELAXED, __HIP_MEMORY_SCOPE_AGENT);
            __hip_atomic_store(gen, g + 1, __ATOMIC_RELEASE, __HIP_MEMORY_SCOPE_AGENT);
        } else {
            while (__hip_atomic_load(gen, __ATOMIC_RELAXED, __HIP_MEMORY_SCOPE_AGENT) == g)
                __builtin_amdgcn_s_sleep(1);
        }
    }
    __syncthreads();
}

// unpack 16 packed u32 (hi|lo<<16) into bf16 hi/lo planes (16 u16 each), 16B-aligned
__device__ inline void unpack16(const u32* w, u16* ph, u16* pl) {
    u32 hd[8], ld[8];
#pragma unroll
    for (int i = 0; i < 8; ++i) {
        hd[i] = (w[2 * i] & 0xFFFFu) | (w[2 * i + 1] << 16);
        ld[i] = (w[2 * i] >> 16) | (w[2 * i + 1] & 0xFFFF0000u);
    }
    *(u32x4*)(ph) = *(const u32x4*)(hd);
    *(u32x4*)(ph + 8) = *(const u32x4*)(hd + 4);
    *(u32x4*)(pl) = *(const u32x4*)(ld);
    *(u32x4*)(pl + 8) = *(const u32x4*)(ld + 4);
}

// dtype-safe staging (pre-phase, normal stores)
__device__ inline void stage(float* dst, const void* src, int n, int gtid, bool isbf) {
    if (isbf) {
        const u16* s = (const u16*)src;
        for (int e = gtid; e < n; e += NALL) dst[e] = bf2f(s[e]);
    } else {
        const float* s = (const float*)src;
        for (int e = gtid; e < n; e += NALL) dst[e] = s[e];
    }
}
__device__ inline void stage_split(u16* hi, u16* lo, const void* src, int n, int gtid, bool isbf) {
    if (isbf) {
        const u16* s = (const u16*)src;
        for (int e = gtid; e < n; e += NALL) { hi[e] = s[e]; lo[e] = 0; }
    } else {
        const float* s = (const float*)src;
        for (int e = gtid; e < n; e += NALL) {
            float w = s[e];
            u16 h = f2bf(w);
            hi[e] = h;
            lo[e] = f2bf(w - bf2f(h));
        }
    }
}

template <bool ISBF>
__device__ inline float ldw(const void* p, size_t i) {
    if constexpr (ISBF) return bf2f(((const u16*)p)[i]);
    else return ((const float*)p)[i];
}

template <bool ISBF>
__device__ void phase5(const void* wih0, const void* emb, const float* __restrict__ condf,
                       const float* __restrict__ bias0f, float* __restrict__ base0,
                       float* __restrict__ embW, int gtid) {
    const int cc = gtid & 2047;
    const int bb0 = gtid >> 11;
    float b = bias0f[cc];
    float a0 = b, a1 = b, a2 = b, a3 = b;
    const float* c0p = condf + (size_t)bb0 * Hn;
    const float* c1p = condf + (size_t)(bb0 + 32) * Hn;
    const float* c2p = condf + (size_t)(bb0 + 64) * Hn;
    const float* c3p = condf + (size_t)(bb0 + 96) * Hn;
    const size_t wb = (size_t)cc * 578 + 64;
    for (int k = 0; k < Hn; ++k) {
        float w = ldw<ISBF>(wih0, wb + k);
        a0 += c0p[k] * w; a1 += c1p[k] * w; a2 += c2p[k] * w; a3 += c3p[k] * w;
    }
    base0[(size_t)bb0 * G4 + cc] = a0;
    base0[(size_t)(bb0 + 32) * G4 + cc] = a1;
    base0[(size_t)(bb0 + 64) * G4 + cc] = a2;
    base0[(size_t)(bb0 + 96) * G4 + cc] = a3;
    float e0 = 0.f, e1 = 0.f, e2 = 0.f, e3 = 0.f;
    const size_t wb2 = (size_t)cc * 578;
    for (int k = 0; k < En; ++k) {
        float w = ldw<ISBF>(wih0, wb2 + k);
        e0 += ldw<ISBF>(emb, (size_t)bb0 * En + k) * w;
        e1 += ldw<ISBF>(emb, (size_t)(bb0 + 32) * En + k) * w;
        e2 += ldw<ISBF>(emb, (size_t)(bb0 + 64) * En + k) * w;
        e3 += ldw<ISBF>(emb, (size_t)(bb0 + 96) * En + k) * w;
    }
    embW[(size_t)bb0 * G4 + cc] = e0;
    embW[(size_t)(bb0 + 32) * G4 + cc] = e1;
    embW[(size_t)(bb0 + 64) * G4 + cc] = e2;
    embW[(size_t)(bb0 + 96) * G4 + cc] = e3;
}

__device__ inline void ln_leaky_row(const float* __restrict__ x, const float* __restrict__ gamma,
                                    const float* __restrict__ beta, float* __restrict__ out,
                                    float* red) {
    int tid = threadIdx.x;
    float v = x[tid];
    float s = v, s2 = v * v;
    for (int off = 32; off; off >>= 1) {
        s += __shfl_down(s, off);
        s2 += __shfl_down(s2, off);
    }
    int wv = tid >> 6;
    if ((tid & 63) == 0) { red[wv * 2] = s; red[wv * 2 + 1] = s2; }
    __syncthreads();
    if (tid == 0) {
        float ts = 0.f, ts2 = 0.f;
        for (int i = 0; i < 8; ++i) { ts += red[i * 2]; ts2 += red[i * 2 + 1]; }
        float m = ts / 512.f;
        float var = ts2 / 512.f - m * m;
        red[16] = m;
        red[17] = rsqrtf(var + 1e-5f);
    }
    __syncthreads();
    float m = red[16], rs = red[17];
    out[tid] = leaky((v - m) * rs * gamma[tid] + beta[tid]);
    __syncthreads();
}

__global__ void init_flags_kernel(int* flags) { flags[threadIdx.x] = 0; }

__global__ __launch_bounds__(NTHR, 1) void gen_kernel(
    const int* __restrict__ char_ids, const void* z, const void* emb,
    const void* cw1, const void* cb1, const void* cg1, const void* cbeta1,
    const void* cw2, const void* cb2, const void* cg2, const void* cbeta2,
    const void* wih0, const void* whh0, const void* bih0, const void* bhh0,
    const void* wih1, const void* whh1, const void* bih1, const void* bhh1,
    const void* wo1, const void* bo1, const void* wo2, const void* bo2,
    const void* init_t, void* outp, char* __restrict__ ws) {
    __shared__ u16 lh0h[16 * LSTR];
    __shared__ u16 lh0l[16 * LSTR];
    __shared__ u16 lh1h[16 * LSTR];
    __shared__ u16 lh1l[16 * LSTR];
    __shared__ float smemx[2048];
    __shared__ float pvs[32];
    __shared__ float red[34];

    int* flags = (int*)(ws + OFF_FLAGS);
    float* b1sum = (float*)(ws + OFF_B1SUM);
    float* wpb = (float*)(ws + OFF_WP);
    float* bias0f = (float*)(ws + OFF_BIAS0);
    float* cpar = (float*)(ws + OFF_CPAR);
    u32* h0p = (u32*)(ws + OFF_H0P);
    u32* h1p = (u32*)(ws + OFF_H1P);
    float* head1f = (float*)(ws + OFF_HEAD1F);
    u16* wo1Th = (u16*)(ws + OFF_WO1TH);
    u16* wo1Tl = (u16*)(ws + OFF_WO1TL);
    float* zf = (float*)(ws + OFF_ZF);
    float* cw1f = (float*)(ws + OFF_CW1F);
    float* cw2f = (float*)(ws + OFF_CW2F);
    float* condf = (float*)(ws + OFF_CONDF);
    float* ybuf = (float*)(ws + OFF_YBUF);
    float* base0 = (float*)(ws + OFF_BASE0);
    float* embW = (float*)(ws + OFF_EMBW);
    u16* W0hi = (u16*)(ws + OFF_W0HI);
    u16* W0lo = (u16*)(ws + OFF_W0LO);
    u16* W1hi = (u16*)(ws + OFF_W1HI);
    u16* W1lo = (u16*)(ws + OFF_W1LO);
    u16* Wi1hi = (u16*)(ws + OFF_WI1HI);
    u16* Wi1lo = (u16*)(ws + OFF_WI1LO);
    float* wo1f = base0;  // temp until P5

    const bool isbf = (((const u32*)cg1)[0] == 0x3F803F80u);

    const int g = blockIdx.x;
    const int tid = threadIdx.x;
    const int wv = tid >> 6;
    const int grp = g >> 4;     // 0..7: 16 batch rows each
    const int ut = g & 15;      // unit block: 32 units
    const int gw = wv & 3;      // gate
    const int ch = wv >> 2;     // col half
    const int R0g = grp * 16;
    const int colb = gw * 512 + ut * 32 + ch * 16;
    const int lane = tid & 63;
    const int n = lane & 15;
    const int q = lane >> 4;
    const int gtid = g * NTHR + tid;
    const f32x4 Z4 = {0.f, 0.f, 0.f, 0.f};

    int* gcnt = flags + 64 * grp;
    int* ggen = flags + 64 * grp + 16;
    int* hcnt = flags + 512;
    int* hgen = flags + 528;

    // ---------------- P0: stage everything ----------------
    cstore1(h0p + gtid, 0);
    cstore1(h1p + gtid, 0);
    stage_split(W0hi, W0lo, whh0, G4 * Hn, gtid, isbf);
    stage_split(W1hi, W1lo, whh1, G4 * Hn, gtid, isbf);
    stage_split(Wi1hi, Wi1lo, wih1, G4 * Hn, gtid, isbf);
    stage(zf, z, Bn * Ln, gtid, isbf);
    stage(cw1f, cw1, Ln * Hn, gtid, isbf);
    stage(cw2f, cw2, Hn * Hn, gtid, isbf);
    stage(cpar + 0, cg1, 512, gtid, isbf);
    stage(cpar + 512, cbeta1, 512, gtid, isbf);
    stage(cpar + 1024, cg2, 512, gtid, isbf);
    stage(cpar + 1536, cbeta2, 512, gtid, isbf);
    stage(cpar + 2048, bo1, 256, gtid, isbf);
    stage(cpar + 2304, bo2, 2, gtid, isbf);
    stage(cpar + 2560, cb2, 512, gtid, isbf);
    stage(cpar + 3072, cb1, 512, gtid, isbf);
    stage(cpar + 3584, wo2, 256 * 2, gtid, isbf);
    stage(wo1f, wo1, Hn * 256, gtid, isbf);
    if (isbf) {
        if (gtid < G4) b1sum[gtid] = bf2f(((const u16*)bih1)[gtid]) + bf2f(((const u16*)bhh1)[gtid]);
        if (gtid < G4) bias0f[gtid] = bf2f(((const u16*)bih0)[gtid]) + bf2f(((const u16*)bhh0)[gtid]);
        if (gtid < 4096) {
            size_t ix = (size_t)(gtid >> 1) * 578 + 576 + (gtid & 1);
            wpb[gtid] = bf2f(((const u16*)wih0)[ix]);
        }
    } else {
        if (gtid < G4) b1sum[gtid] = ((const float*)bih1)[gtid] + ((const float*)bhh1)[gtid];
        if (gtid < G4) bias0f[gtid] = ((const float*)bih0)[gtid] + ((const float*)bhh0)[gtid];
        if (gtid < 4096) {
            size_t ix = (size_t)(gtid >> 1) * 578 + 576 + (gtid & 1);
            wpb[gtid] = ((const float*)wih0)[ix];
        }
    }
    gbar_heavy(hcnt, hgen);
    // ---------------- P1 ----------------
    {
        int bb = gtid >> 9, nn = gtid & 511;
        float a = cpar[3072 + nn];
        const float* zr = zf + bb * Ln;
        for (int k = 0; k < Ln; ++k) a += zr[k] * cw1f[k * Hn + nn];
        ybuf[gtid] = a;
    }
    for (int e = gtid; e < 256 * Hn; e += NALL) {
        int nn = e >> 9, kk = e & 511;
        float w = wo1f[kk * 256 + nn];
        u16 hv = f2bf(w);
        wo1Th[e] = hv;
        wo1Tl[e] = f2bf(w - bf2f(hv));
    }
    gbar_heavy(hcnt, hgen);
    ln_leaky_row(ybuf + g * Hn, cpar + 0, cpar + 512, condf + g * Hn, red);
    gbar_heavy(hcnt, hgen);
    {
        float a = cpar[2560 + tid];
        const float* crow = condf + g * Hn;
        for (int k = 0; k < Hn; ++k) a += crow[k] * cw2f[k * Hn + tid];
        ybuf[g * Hn + tid] = a;
    }
    gbar_heavy(hcnt, hgen);
    ln_leaky_row(ybuf + g * Hn, cpar + 1024, cpar + 1536, condf + g * Hn, red);
    gbar_heavy(hcnt, hgen);
    if (isbf) phase5<true>(wih0, emb, condf, bias0f, base0, embW, gtid);
    else phase5<false>(wih0, emb, condf, bias0f, base0, embW, gtid);
    gbar_heavy(hcnt, hgen);  // invalidates L2: cached reads below see fresh data

    // ---------------- main loop ----------------
    float c0 = 0.f, c1 = 0.f;
    const int bb = R0g + (tid >> 5);
    const int uu = ut * 32 + (tid & 31);
    const float* bo1f = cpar + 2048;
    const float* bo2f = cpar + 2304;
    const float* wo2f = cpar + 3584;
    const int srow = tid >> 5;         // staging row 0..15
    const int kof = (tid & 31) * 16;   // staging k offset (u32 elems)
    f32x4 acc1 = Z4;

    // init: zero h0 planes (h0(-1)=0); pvs init
    for (int e = tid; e < 16 * LSTR; e += NTHR) { lh0h[e] = 0; lh0l[e] = 0; }
    if (tid < 32) pvs[tid] = isbf ? bf2f(((const u16*)init_t)[tid & 1])
                                  : ((const float*)init_t)[tid & 1];

    for (int t = 0; t < Tn; ++t) {
        // ---- X: stage h1(t-1); GEMM whh0·h0 + whh1·h1; wave0 also head1(t-1) ----
        {
            u32 w[16];
            cload16(h1p + (size_t)(R0g + srow) * Hn + kof, w);
            unpack16(w, lh1h + srow * LSTR + kof, lh1l + srow * LSTR + kof);
        }
        __syncthreads();
        f32x4 x0a = Z4, x0b = Z4, x0c = Z4, x1a = Z4, x1b = Z4, x1c = Z4;
        {
            const int arow = n * LSTR;
            const u16* B0h = W0hi + (size_t)(colb + n) * Hn;
            const u16* B0l = W0lo + (size_t)(colb + n) * Hn;
            const u16* B1h = W1hi + (size_t)(colb + n) * Hn;
            const u16* B1l = W1lo + (size_t)(colb + n) * Hn;
#pragma unroll 4
            for (int it = 0; it < 16; ++it) {
                const int ko = it * 32 + q * 8;
                bf16x8 a0h = *(const bf16x8*)(lh0h + arow + ko);
                bf16x8 a0l = *(const bf16x8*)(lh0l + arow + ko);
                bf16x8 a1h = *(const bf16x8*)(lh1h + arow + ko);
                bf16x8 a1l = *(const bf16x8*)(lh1l + arow + ko);
                bf16x8 b0h = *(const bf16x8*)(B0h + ko);
                bf16x8 b0l = *(const bf16x8*)(B0l + ko);
                bf16x8 b1h = *(const bf16x8*)(B1h + ko);
                bf16x8 b1l = *(const bf16x8*)(B1l + ko);
                x0a = __builtin_amdgcn_mfma_f32_16x16x32_bf16(a0h, b0h, x0a, 0, 0, 0);
                x0b = __builtin_amdgcn_mfma_f32_16x16x32_bf16(a0l, b0h, x0b, 0, 0, 0);
                x0c = __builtin_amdgcn_mfma_f32_16x16x32_bf16(a0h, b0l, x0c, 0, 0, 0);
                x1a = __builtin_amdgcn_mfma_f32_16x16x32_bf16(a1h, b1h, x1a, 0, 0, 0);
                x1b = __builtin_amdgcn_mfma_f32_16x16x32_bf16(a1l, b1h, x1b, 0, 0, 0);
                x1c = __builtin_amdgcn_mfma_f32_16x16x32_bf16(a1h, b1l, x1c, 0, 0, 0);
            }
        }
        f32x4 acc0 = x0a + x0b + x0c;
        acc1 = x1a + x1b + x1c;
        if (wv == 0 && t >= 1) {  // head1 tile (16 rows x 16 cols, K=512) from staged h1
            f32x4 h1s = Z4, h2s = Z4, h3s = Z4;
            const int c0h = ut * 16;
            const u16* Bh = wo1Th + (size_t)(c0h + n) * Hn;
            const u16* Bl = wo1Tl + (size_t)(c0h + n) * Hn;
            const int arow = n * LSTR;
#pragma unroll 4
            for (int it = 0; it < 16; ++it) {
                const int ko = it * 32 + q * 8;
                bf16x8 ah = *(const bf16x8*)(lh1h + arow + ko);
                bf16x8 al = *(const bf16x8*)(lh1l + arow + ko);
                bf16x8 vh = *(const bf16x8*)(Bh + ko);
                bf16x8 vl = *(const bf16x8*)(Bl + ko);
                h1s = __builtin_amdgcn_mfma_f32_16x16x32_bf16(ah, vh, h1s, 0, 0, 0);
                h2s = __builtin_amdgcn_mfma_f32_16x16x32_bf16(al, vh, h2s, 0, 0, 0);
                h3s = __builtin_amdgcn_mfma_f32_16x16x32_bf16(ah, vl, h3s, 0, 0, 0);
            }
            f32x4 hh = h1s + h2s + h3s;
#pragma unroll
            for (int r = 0; r < 4; ++r) {
                int cc = c0h + n;
                cstoref(head1f + (size_t)(R0g + q * 4 + r) * 256 + cc, leaky(hh[r] + bo1f[cc]));
            }
        }
        gbar_light(gcnt, ggen, 16);

        // ---- Y: head2 (redundant per WG) + gates0 -> h0(t) ----
#pragma unroll
        for (int r = 0; r < 4; ++r)
            smemx[gw * 512 + (q * 4 + r) * 32 + ch * 16 + n] = acc0[r];
        if (t >= 1) {
            const int pr = tid >> 4;          // 0..31: (row 0..15) x (j 0..1)
            const int rowl = pr >> 1, jo = pr & 1;
            const int ks = (tid & 15) * 16;
            u32 hw[16];
            cload16((const u32*)(head1f + (size_t)(R0g + rowl) * 256 + ks), hw);
            float s = 0.f;
#pragma unroll
            for (int i = 0; i < 16; ++i) s += u2f(hw[i]) * wo2f[(ks + i) * 2 + jo];
            s += __shfl_xor(s, 1, 16);
            s += __shfl_xor(s, 2, 16);
            s += __shfl_xor(s, 4, 16);
            s += __shfl_xor(s, 8, 16);
            if ((tid & 15) == 0) {
                float y = softplus(s + bo2f[jo]) + 0.005f;
                pvs[pr] = y;
                if (ut == 0) {
                    size_t oi = ((size_t)(R0g + rowl) * Tn + (t - 1)) * 2 + jo;
                    if (isbf) ((u16*)outp)[oi] = f2bf(y);
                    else ((float*)outp)[oi] = y;
                }
            }
        }
        __syncthreads();
        {
            int id = char_ids[bb * Tn + t];
            float pv0 = pvs[(tid >> 5) * 2], pv1 = pvs[(tid >> 5) * 2 + 1];
            float gv[4];
#pragma unroll
            for (int gi = 0; gi < 4; ++gi) {
                int cc = gi * 512 + uu;
                gv[gi] = smemx[gi * 512 + (tid >> 5) * 32 + (tid & 31)] +
                         base0[(size_t)bb * G4 + cc] + embW[(size_t)id * G4 + cc] +
                         pv0 * wpb[2 * cc] + pv1 * wpb[2 * cc + 1];
            }
            float ig = sigm(gv[0]), fg = sigm(gv[1]), gg = tanhf(gv[2]), og = sigm(gv[3]);
            c0 = fg * c0 + ig * gg;
            float h = og * tanhf(c0);
            u16 hv = f2bf(h);
            u16 lv = f2bf(h - bf2f(hv));
            cstore1(h0p + (size_t)bb * Hn + uu, (u32)hv | ((u32)lv << 16));
        }
        gbar_light(gcnt, ggen, 16);

        // ---- Z: stage h0(t); GEMM wih1·h0(t); gates1 -> h1(t) ----
        {
            u32 w[16];
            cload16(h0p + (size_t)(R0g + srow) * Hn + kof, w);
            unpack16(w, lh0h + srow * LSTR + kof, lh0l + srow * LSTR + kof);
        }
        __syncthreads();
        {
            const int arow = n * LSTR;
            const u16* Bh = Wi1hi + (size_t)(colb + n) * Hn;
            const u16* Bl = Wi1lo + (size_t)(colb + n) * Hn;
            f32x4 za = Z4, zb = Z4, zc = Z4;
#pragma unroll 4
            for (int it = 0; it < 16; ++it) {
                const int ko = it * 32 + q * 8;
                bf16x8 ah = *(const bf16x8*)(lh0h + arow + ko);
                bf16x8 al = *(const bf16x8*)(lh0l + arow + ko);
                bf16x8 bh = *(const bf16x8*)(Bh + ko);
                bf16x8 bl = *(const bf16x8*)(Bl + ko);
                za = __builtin_amdgcn_mfma_f32_16x16x32_bf16(ah, bh, za, 0, 0, 0);
                zb = __builtin_amdgcn_mfma_f32_16x16x32_bf16(al, bh, zb, 0, 0, 0);
                zc = __builtin_amdgcn_mfma_f32_16x16x32_bf16(ah, bl, zc, 0, 0, 0);
            }
            acc1 = acc1 + za + zb + zc;
        }
        __syncthreads();
#pragma unroll
        for (int r = 0; r < 4; ++r)
            smemx[gw * 512 + (q * 4 + r) * 32 + ch * 16 + n] = acc1[r];
        __syncthreads();
        {
            float gv[4];
#pragma unroll
            for (int gi = 0; gi < 4; ++gi) {
                int cc = gi * 512 + uu;
                gv[gi] = smemx[gi * 512 + (tid >> 5) * 32 + (tid & 31)] + b1sum[cc];
            }
            float ig = sigm(gv[0]), fg = sigm(gv[1]), gg = tanhf(gv[2]), og = sigm(gv[3]);
            c1 = fg * c1 + ig * gg;
            float h = og * tanhf(c1);
            u16 hv = f2bf(h);
            u16 lv = f2bf(h - bf2f(hv));
            cstore1(h1p + (size_t)bb * Hn + uu, (u32)hv | ((u32)lv << 16));
        }
        gbar_light(gcnt, ggen, 16);
    }

    // ---------------- epilogue: head for t=511 ----------------
    {
        u32 w[16];
        cload16(h1p + (size_t)(R0g + srow) * Hn + kof, w);
        unpack16(w, lh1h + srow * LSTR + kof, lh1l + srow * LSTR + kof);
    }
    __syncthreads();
    if (wv == 0) {
        f32x4 h1s = Z4, h2s = Z4, h3s = Z4;
        const int c0h = ut * 16;
        const u16* Bh = wo1Th + (size_t)(c0h + n) * Hn;
        const u16* Bl = wo1Tl + (size_t)(c0h + n) * Hn;
        const int arow = n * LSTR;
#pragma unroll 4
        for (int it = 0; it < 16; ++it) {
            const int ko = it * 32 + q * 8;
            bf16x8 ah = *(const bf16x8*)(lh1h + arow + ko);
            bf16x8 al = *(const bf16x8*)(lh1l + arow + ko);
            bf16x8 vh = *(const bf16x8*)(Bh + ko);
            bf16x8 vl = *(const bf16x8*)(Bl + ko);
            h1s = __builtin_amdgcn_mfma_f32_16x16x32_bf16(ah, vh, h1s, 0, 0, 0);
            h2s = __builtin_amdgcn_mfma_f32_16x16x32_bf16(al, vh, h2s, 0, 0, 0);
            h3s = __builtin_amdgcn_mfma_f32_16x16x32_bf16(ah, vl, h3s, 0, 0, 0);
        }
        f32x4 hh = h1s + h2s + h3s;
#pragma unroll
        for (int r = 0; r < 4; ++r) {
            int cc = c0h + n;
            cstoref(head1f + (size_t)(R0g + q * 4 + r) * 256 + cc, leaky(hh[r] + bo1f[cc]));
        }
    }
    gbar_light(gcnt, ggen, 16);
    if (ut == 0) {
        const int pr = tid >> 4;
        const int rowl = pr >> 1, jo = pr & 1;
        const int ks = (tid & 15) * 16;
        u32 hw[16];
        cload16((const u32*)(head1f + (size_t)(R0g + rowl) * 256 + ks), hw);
        float s = 0.f;
#pragma unroll
        for (int i = 0; i < 16; ++i) s += u2f(hw[i]) * wo2f[(ks + i) * 2 + jo];
        s += __shfl_xor(s, 1, 16);
        s += __shfl_xor(s, 2, 16);
        s += __shfl_xor(s, 4, 16);
        s += __shfl_xor(s, 8, 16);
        if ((tid & 15) == 0) {
            float y = softplus(s + bo2f[jo]) + 0.005f;
            size_t oi = ((size_t)(R0g + rowl) * Tn + (Tn - 1)) * 2 + jo;
            if (isbf) ((u16*)outp)[oi] = f2bf(y);
            else ((float*)outp)[oi] = y;
        }
    }
}

extern "C" void kernel_launch(void* const* d_in, const int* in_sizes, int n_in,
                              void* d_out, int out_size, void* d_ws, size_t ws_size,
                              hipStream_t stream) {
    (void)in_sizes; (void)n_in; (void)out_size; (void)ws_size;
    init_flags_kernel<<<1, 1024, 0, stream>>>((int*)d_ws);
    gen_kernel<<<WGS, NTHR, 0, stream>>>(
        (const int*)d_in[0], d_in[1], d_in[2], d_in[3], d_in[4], d_in[5], d_in[6], d_in[7],
        d_in[8], d_in[9], d_in[10], d_in[11], d_in[12], d_in[13], d_in[14], d_in[15], d_in[16],
        d_in[17], d_in[18], d_in[19], d_in[20], d_in[21], d_in[22], d_in[23],
        d_out, (char*)d_ws);
}